// Round 7
// baseline (631.499 us; speedup 1.0000x reference)
//
#include <hip/hip_runtime.h>
#include <hip/hip_bf16.h>
#include <hip/hip_fp16.h>

// Problem dims (hard-coded): B=8, S=4096, DIM=1024, M=1024
// Algebraic restructure: attn = x @ (mem·W)^T + (mem·b); softmax; out = probs @ mem
// Round 7: (1) gemm_attn gets a true counted-vmcnt pipeline: x prefetch 2
// K-tiles ahead (double reg buffer), vmcnt(8)/vmcnt(4) counted waits, no
// vmcnt(0) drain in steady state. (2) fused softmax+ctx replaced by proven
// softmax_k (fp16 probs) + gemm_ctx: 256x256 4-phase tiled fp16 GEMM with
// g2l16-staged A(probs) and B(memT), BK=64 double-buffer, XOR swizzle.
#define KDIM 1024

typedef __attribute__((ext_vector_type(8))) __bf16    bf16x8;
typedef __attribute__((ext_vector_type(4))) __bf16    bf16x4;
typedef __attribute__((ext_vector_type(8))) _Float16  half8;
typedef __attribute__((ext_vector_type(4))) _Float16  half4v;
typedef __attribute__((ext_vector_type(4))) float     f32x4;

// async global->LDS, 16B per lane. LDS base must be wave-uniform; HW adds lane*16.
__device__ __forceinline__ void g2l16(const void* g, void* l) {
  __builtin_amdgcn_global_load_lds(
      (const __attribute__((address_space(1))) unsigned int*)g,
      (__attribute__((address_space(3))) unsigned int*)l, 16, 0, 0);
}

__device__ __forceinline__ void split2(float v, __bf16& h, __bf16& l) {
  h = (__bf16)v;
  l = (__bf16)(v - (float)h);
}

// ---------------------------------------------------------------------------
// split mem into bf16 hi/lo (row-major [m][e], already B^T/A layout for P-GEMM)
__global__ __launch_bounds__(256) void split_mem(
    const float* __restrict__ mem, __bf16* __restrict__ Mh, __bf16* __restrict__ Ml) {
  int i = blockIdx.x * 256 + threadIdx.x;   // 1M threads
  __bf16 h, l;
  split2(mem[i], h, l);
  Mh[i] = h; Ml[i] = l;
}

// transpose W [e][d] -> Wt [d][e], split to bf16 hi/lo (B^T layout for P-GEMM)
__global__ __launch_bounds__(256) void transpose_split_W(
    const float* __restrict__ W, __bf16* __restrict__ Wth, __bf16* __restrict__ Wtl) {
  __shared__ float tl[32][33];
  int bx = blockIdx.x, by = blockIdx.y;
  int tx = threadIdx.x, ty = threadIdx.y;   // (32, 8)
#pragma unroll
  for (int j = 0; j < 4; ++j)
    tl[ty + 8 * j][tx] = W[(by * 32 + ty + 8 * j) * 1024 + bx * 32 + tx];
  __syncthreads();
#pragma unroll
  for (int j = 0; j < 4; ++j) {
    float v = tl[tx][ty + 8 * j];
    __bf16 h, l;
    split2(v, h, l);
    const int idx = (bx * 32 + ty + 8 * j) * 1024 + by * 32 + tx;
    Wth[idx] = h; Wtl[idx] = l;
  }
}

// transpose mem [m][d] -> memT fp16 [d][m] (B^T layout for context GEMM)
__global__ __launch_bounds__(256) void transpose_mem(
    const float* __restrict__ mem, _Float16* __restrict__ memT) {
  __shared__ float tl[32][33];
  int bx = blockIdx.x, by = blockIdx.y;
  int tx = threadIdx.x, ty = threadIdx.y;   // (32, 8)
#pragma unroll
  for (int j = 0; j < 4; ++j)
    tl[ty + 8 * j][tx] = mem[(by * 32 + ty + 8 * j) * 1024 + bx * 32 + tx];
  __syncthreads();
#pragma unroll
  for (int j = 0; j < 4; ++j)
    memT[(bx * 32 + ty + 8 * j) * 1024 + by * 32 + tx] =
        (_Float16)tl[tx][ty + 8 * j];
}

// c[m] = sum_e b[e] * mem[m][e]  (fp32). One wave per row.
__global__ __launch_bounds__(256) void bias_c(
    const float* __restrict__ b, const float* __restrict__ mem,
    float* __restrict__ c) {
  const int wave = threadIdx.x >> 6, lane = threadIdx.x & 63;
  const int row = blockIdx.x * 4 + wave;
  float s = 0.f;
#pragma unroll
  for (int j = 0; j < 16; ++j) {
    const int e = lane + 64 * j;
    s += b[e] * mem[row * 1024 + e];
  }
#pragma unroll
  for (int off = 32; off; off >>= 1) s += __shfl_xor(s, off);
  if (lane == 0) c[row] = s;
}

// ---------------------------------------------------------------------------
// Split-bf16 compensated GEMM for the small P = mem @ W product
// (128x128 tile, known-good structure). Epilogue writes C as bf16 hi/lo.
__global__ __launch_bounds__(256) void gemm_p(
    const __bf16* __restrict__ Agh, const __bf16* __restrict__ Agl,
    const __bf16* __restrict__ Bgh, const __bf16* __restrict__ Bgl,
    __bf16* __restrict__ Oh, __bf16* __restrict__ Ol) {
  __shared__ __attribute__((aligned(16))) __bf16 Ah[128 * 32];
  __shared__ __attribute__((aligned(16))) __bf16 Al[128 * 32];
  __shared__ __attribute__((aligned(16))) __bf16 Bh[128 * 32];
  __shared__ __attribute__((aligned(16))) __bf16 Bl[128 * 32];

  const int t = threadIdx.x;
  const int wave = t >> 6;
  const int lane = t & 63;
  const int wm = wave & 1, wn = wave >> 1;

  const int nwg = gridDim.x * gridDim.y;
  int flat = blockIdx.y * gridDim.x + blockIdx.x;
  if ((nwg & 7) == 0) {
    const int cpx = nwg >> 3;
    flat = (flat & 7) * cpx + (flat >> 3);
  }
  const int tileN = (flat % gridDim.x) * 128;
  const int tileM = (flat / gridDim.x) * 128;

  f32x4 acc[4][4] = {};

  const int rS = lane >> 2;
  const int cS = (lane & 3) * 8;

  for (int kt = 0; kt < KDIM / 32; ++kt) {
    const int k0 = kt * 32;
    __syncthreads();
#pragma unroll
    for (int i = 0; i < 2; ++i) {
      const int rb = i * 64 + wave * 16;
      const int grb = (tileN + rb + rS) * KDIM + k0 + cS;
      g2l16(Bgh + grb, &Bh[rb * 32]);
      g2l16(Bgl + grb, &Bl[rb * 32]);
      const int gra = (tileM + rb + rS) * KDIM + k0 + cS;
      g2l16(Agh + gra, &Ah[rb * 32]);
      g2l16(Agl + gra, &Al[rb * 32]);
    }
    __syncthreads();

    const int fr = lane & 15;
    const int fk = (lane >> 4) * 8;
    bf16x8 afh[4], afl[4], bfh[4], bfl[4];
#pragma unroll
    for (int mf = 0; mf < 4; ++mf) {
      const int r = wm * 64 + mf * 16 + fr;
      afh[mf] = *(const bf16x8*)(&Ah[r * 32 + fk]);
      afl[mf] = *(const bf16x8*)(&Al[r * 32 + fk]);
    }
#pragma unroll
    for (int nf = 0; nf < 4; ++nf) {
      const int r = wn * 64 + nf * 16 + fr;
      bfh[nf] = *(const bf16x8*)(&Bh[r * 32 + fk]);
      bfl[nf] = *(const bf16x8*)(&Bl[r * 32 + fk]);
    }
#pragma unroll
    for (int mf = 0; mf < 4; ++mf)
#pragma unroll
      for (int nf = 0; nf < 4; ++nf) {
        acc[mf][nf] = __builtin_amdgcn_mfma_f32_16x16x32_bf16(afh[mf], bfh[nf], acc[mf][nf], 0, 0, 0);
        acc[mf][nf] = __builtin_amdgcn_mfma_f32_16x16x32_bf16(afh[mf], bfl[nf], acc[mf][nf], 0, 0, 0);
        acc[mf][nf] = __builtin_amdgcn_mfma_f32_16x16x32_bf16(afl[mf], bfh[nf], acc[mf][nf], 0, 0, 0);
      }
  }

  const int er = (lane >> 4) * 4;
  const int ec = lane & 15;
#pragma unroll
  for (int nf = 0; nf < 4; ++nf) {
    const int col = tileN + wn * 64 + nf * 16 + ec;
#pragma unroll
    for (int mf = 0; mf < 4; ++mf) {
#pragma unroll
      for (int r = 0; r < 4; ++r) {
        const int row = tileM + wm * 64 + mf * 16 + er + r;
        const size_t idx = (size_t)row * KDIM + col;
        float v = acc[mf][nf][r];
        __bf16 h = (__bf16)v;
        Oh[idx] = h;
        Ol[idx] = (__bf16)(v - (float)h);
      }
    }
  }
}

// ---------------------------------------------------------------------------
// attn = x @ P^T + c : 256x256 tile, BK=32, 8 waves, 4 quadrant-phases/K-tile.
// Round-7 sync scheme (T4 counted vmcnt, no steady-state drain):
//   per kt VMEM order: P0 stageB(kt+1)[4 g2l16] -> P1 xload(kt+2)[4 loads]
//   P2: vmcnt(8) -> consume x(kt+1) (2 tiles / ~6 phases old)
//   P3: vmcnt(4) -> only B-stage waited; x stays in flight. lgkmcnt(0) for
//   the ds_writes. Numerics identical to rounds 5/6.
__global__ __launch_bounds__(512, 2) void gemm_attn_8ph(
    const float* __restrict__ X,
    const __bf16* __restrict__ Pgh, const __bf16* __restrict__ Pgl,
    const float* __restrict__ bias,
    float* __restrict__ Of) {
  __shared__ __attribute__((aligned(16))) __bf16 AhL[2 * 8192];
  __shared__ __attribute__((aligned(16))) __bf16 AlL[2 * 8192];
  __shared__ __attribute__((aligned(16))) __bf16 BhL[2 * 8192];
  __shared__ __attribute__((aligned(16))) __bf16 BlL[2 * 8192];

  const int t = threadIdx.x;
  const int wave = t >> 6, lane = t & 63;
  const int wm = wave >> 2;        // 2 M-halves (128 rows each)
  const int wn = wave & 3;         // 4 N-quarters (64 cols each)

  // XCD-aware bijective remap; nwg = 4*128 = 512
  int flat = blockIdx.y * 4 + blockIdx.x;
  flat = (flat & 7) * 64 + (flat >> 3);
  const int tileN = (flat & 3) * 256;
  const int tileM = (flat >> 2) * 256;

  // ---- staging geometry
  int rowB_[2], gsB_[2], ldsB_[2];
#pragma unroll
  for (int i = 0; i < 2; ++i) {
    const int f16 = i * 512 + t;
    rowB_[i] = f16 >> 2;
    const int slot = f16 & 3;
    gsB_[i] = slot ^ ((rowB_[i] >> 1) & 3);       // pre-swizzled src col group
    ldsB_[i] = (i * 512 + wave * 64) * 8;         // wave-uniform elem base
  }
  int rowA_[4], colA_[4], physA_[4];
#pragma unroll
  for (int i = 0; i < 4; ++i) {
    const int f4 = i * 512 + t;
    rowA_[i] = f4 >> 3;
    const int col8 = f4 & 7;
    colA_[i] = col8 * 4;
    physA_[i] = rowA_[i] * 64 +
                ((((col8 >> 1) ^ ((rowA_[i] >> 1) & 3)) << 4)) + (col8 & 1) * 8;
  }

  const int fr = lane & 15;
  const int sc = lane >> 4;
  const int swF = (fr >> 1) & 3;
  const int fragoff = ((sc ^ swF) << 4);

  f32x4 acc[8][4] = {};
  f32x4 xrA[4], xrB[4];

  auto xload = [&](f32x4 (&dst)[4], int k0) {
#pragma unroll
    for (int i = 0; i < 4; ++i)
      dst[i] = *(const f32x4*)(X + (size_t)(tileM + rowA_[i]) * 1024 + k0 + colA_[i]);
  };
  auto stageB = [&](int buf, int k0) {
#pragma unroll
    for (int i = 0; i < 2; ++i) {
      const size_t g = (size_t)(tileN + rowB_[i]) * 1024 + k0 + gsB_[i] * 8;
      g2l16(Pgh + g, &BhL[buf * 8192 + ldsB_[i]]);
      g2l16(Pgl + g, &BlL[buf * 8192 + ldsB_[i]]);
    }
  };
  auto xwrite = [&](const f32x4 (&src)[4], int buf) {
#pragma unroll
    for (int i = 0; i < 4; ++i) {
      bf16x4 h, l;
#pragma unroll
      for (int j = 0; j < 4; ++j) {
        const float vj = src[i][j];
        __bf16 hh = (__bf16)vj;
        h[j] = hh;
        l[j] = (__bf16)(vj - (float)hh);
      }
      *(bf16x4*)((char*)AhL + buf * 16384 + physA_[i]) = h;
      *(bf16x4*)((char*)AlL + buf * 16384 + physA_[i]) = l;
    }
  };
  auto mm3 = [&](f32x4& a, const bf16x8& ah, const bf16x8& al,
                 const bf16x8& bh, const bf16x8& bl) {
    a = __builtin_amdgcn_mfma_f32_16x16x32_bf16(ah, bh, a, 0, 0, 0);
    a = __builtin_amdgcn_mfma_f32_16x16x32_bf16(ah, bl, a, 0, 0, 0);
    a = __builtin_amdgcn_mfma_f32_16x16x32_bf16(al, bh, a, 0, 0, 0);
  };

  // ---- prologue: tile 0 into buffer 0; x(1) prefetched into xrB
  xload(xrA, 0);             // x(0)
  stageB(0, 0);              // B(0): 4 g2l16
  xwrite(xrA, 0);            // compiler-counted wait on x(0); B(0) in flight
  xload(xrB, 32);            // x(1)
  asm volatile("s_waitcnt vmcnt(4) lgkmcnt(0)" ::: "memory");  // B(0) done
  __builtin_amdgcn_s_barrier();

  auto ktbody = [&](int kt, f32x4 (&xcons)[4], f32x4 (&xldst)[4]) {
    const int cur = kt & 1, nxt = cur ^ 1;
    bf16x8 ah[4], al[4], b0h[2], b0l[2], b1h[2], b1l[2];

    // ---- P0: read A m0-3 + B n0-1; issue stageB(kt+1)
#pragma unroll
    for (int mf = 0; mf < 4; ++mf) {
      const int row = wm * 128 + mf * 16 + fr;
      const int off = cur * 16384 + row * 64 + fragoff;
      ah[mf] = *(const bf16x8*)((const char*)AhL + off);
      al[mf] = *(const bf16x8*)((const char*)AlL + off);
    }
#pragma unroll
    for (int nf = 0; nf < 2; ++nf) {
      const int row = wn * 64 + nf * 16 + fr;
      const int off = cur * 16384 + row * 64 + fragoff;
      b0h[nf] = *(const bf16x8*)((const char*)BhL + off);
      b0l[nf] = *(const bf16x8*)((const char*)BlL + off);
    }
    if (kt < 31) stageB(nxt, (kt + 1) * 32);
    __builtin_amdgcn_s_barrier();
    __builtin_amdgcn_s_setprio(1);
#pragma unroll
    for (int mf = 0; mf < 4; ++mf)
#pragma unroll
      for (int nf = 0; nf < 2; ++nf)
        mm3(acc[mf][nf], ah[mf], al[mf], b0h[nf], b0l[nf]);
    __builtin_amdgcn_s_setprio(0);
    __builtin_amdgcn_s_barrier();

    // ---- P1: read B n2-3; issue xload(kt+2); MFMA m0-3 x n2-3
#pragma unroll
    for (int nf = 0; nf < 2; ++nf) {
      const int row = wn * 64 + (2 + nf) * 16 + fr;
      const int off = cur * 16384 + row * 64 + fragoff;
      b1h[nf] = *(const bf16x8*)((const char*)BhL + off);
      b1l[nf] = *(const bf16x8*)((const char*)BlL + off);
    }
    if (kt < 30) xload(xldst, (kt + 2) * 32);
    __builtin_amdgcn_s_barrier();
    __builtin_amdgcn_s_setprio(1);
#pragma unroll
    for (int mf = 0; mf < 4; ++mf)
#pragma unroll
      for (int nf = 0; nf < 2; ++nf)
        mm3(acc[mf][2 + nf], ah[mf], al[mf], b1h[nf], b1l[nf]);
    __builtin_amdgcn_s_setprio(0);
    __builtin_amdgcn_s_barrier();

    // ---- P2: read A m4-7; counted-wait then write next A; MFMA m4-7 x n0-1
#pragma unroll
    for (int mf = 0; mf < 4; ++mf) {
      const int row = wm * 128 + (4 + mf) * 16 + fr;
      const int off = cur * 16384 + row * 64 + fragoff;
      ah[mf] = *(const bf16x8*)((const char*)AhL + off);
      al[mf] = *(const bf16x8*)((const char*)AlL + off);
    }
    if (kt < 31) {
      if (kt < 30)
        asm volatile("s_waitcnt vmcnt(8)" ::: "memory");   // x(kt+1) done; B+x newer stay
      else
        asm volatile("s_waitcnt vmcnt(4)" ::: "memory");   // kt==30: no x(32) issued
      xwrite(xcons, nxt);
    }
    __builtin_amdgcn_s_barrier();
    __builtin_amdgcn_s_setprio(1);
#pragma unroll
    for (int mf = 0; mf < 4; ++mf)
#pragma unroll
      for (int nf = 0; nf < 2; ++nf)
        mm3(acc[4 + mf][nf], ah[mf], al[mf], b0h[nf], b0l[nf]);
    __builtin_amdgcn_s_setprio(0);
    __builtin_amdgcn_s_barrier();

    // ---- P3: MFMA m4-7 x n2-3; counted tile-end wait (B-stage only)
    __builtin_amdgcn_s_setprio(1);
#pragma unroll
    for (int mf = 0; mf < 4; ++mf)
#pragma unroll
      for (int nf = 0; nf < 2; ++nf)
        mm3(acc[4 + mf][2 + nf], ah[mf], al[mf], b1h[nf], b1l[nf]);
    __builtin_amdgcn_s_setprio(0);
    if (kt < 30)
      asm volatile("s_waitcnt vmcnt(4) lgkmcnt(0)" ::: "memory");  // B(kt+1) done, x(kt+2) flies
    else if (kt == 30)
      asm volatile("s_waitcnt vmcnt(0) lgkmcnt(0)" ::: "memory");  // only B(31) left
    __builtin_amdgcn_s_barrier();
  };

  for (int kt = 0; kt < 32; kt += 2) {
    ktbody(kt, xrB, xrA);      // even kt: consume x(kt+1) in xrB, load into xrA
    ktbody(kt + 1, xrA, xrB);  // odd  kt: consume xrA, load into xrB
  }

  // ---- epilogue: C/D layout col = lane&15, row = (lane>>4)*4 + reg; + bias
  const int er = (lane >> 4) * 4;
  const int ec = lane & 15;
#pragma unroll
  for (int nf = 0; nf < 4; ++nf) {
    const int col = tileN + wn * 64 + nf * 16 + ec;
    const float bv = bias[col];
#pragma unroll
    for (int mf = 0; mf < 8; ++mf) {
#pragma unroll
      for (int r = 0; r < 4; ++r) {
        const int row = tileM + wm * 128 + mf * 16 + er + r;
        Of[(size_t)row * 1024 + col] = acc[mf][nf][r] + bv;
      }
    }
  }
}

// ---------------------------------------------------------------------------
// softmax over M=1024 per row; attn fp32 in, probs fp16 out. 1 row / block.
// (r0's proven kernel, unchanged numerics.)
__global__ __launch_bounds__(256) void softmax_k(
    const float* __restrict__ attn, _Float16* __restrict__ probs) {
  const int row = blockIdx.x;
  const int t = threadIdx.x;
  const int wave = t >> 6, lane = t & 63;
  __shared__ float redm[4];
  __shared__ float reds[4];

  float4 v = ((const float4*)(attn + (size_t)row * 1024))[t];
  float m = fmaxf(fmaxf(v.x, v.y), fmaxf(v.z, v.w));
#pragma unroll
  for (int off = 32; off; off >>= 1) m = fmaxf(m, __shfl_xor(m, off));
  if (lane == 0) redm[wave] = m;
  __syncthreads();
  m = fmaxf(fmaxf(redm[0], redm[1]), fmaxf(redm[2], redm[3]));

  float e0 = expf(v.x - m), e1 = expf(v.y - m);
  float e2 = expf(v.z - m), e3 = expf(v.w - m);
  float s = e0 + e1 + e2 + e3;
#pragma unroll
  for (int off = 32; off; off >>= 1) s += __shfl_xor(s, off);
  if (lane == 0) reds[wave] = s;
  __syncthreads();
  s = reds[0] + reds[1] + reds[2] + reds[3];
  const float inv = 1.0f / s;

  half4v o;
  o[0] = (_Float16)(e0 * inv);
  o[1] = (_Float16)(e1 * inv);
  o[2] = (_Float16)(e2 * inv);
  o[3] = (_Float16)(e3 * inv);
  ((half4v*)(probs + (size_t)row * 1024))[t] = o;
}

// ---------------------------------------------------------------------------
// context = probs @ memT^T : 256x256 tile, BK=64 double-buffered, 8 waves,
// fp16 single-product. A(probs) and B(memT) both g2l16-staged with row-XOR
// slot swizzle (8 slots/row, slot ^= row&7). 4 phases x 2 kk per super-step;
// stage issued at kk0-Pa, drained (vmcnt(0)) at kk1-Pb end (~7 phases cover).
// K-chunks consumed in ascending order (numerics = r0 gemm3 / r5 fused).
__global__ __launch_bounds__(512, 2) void gemm_ctx(
    const _Float16* __restrict__ probs, const _Float16* __restrict__ memT,
    float* __restrict__ Of) {
  __shared__ __attribute__((aligned(16))) _Float16 Asd[2 * 16384];  // 64 KB
  __shared__ __attribute__((aligned(16))) _Float16 Bsd[2 * 16384];  // 64 KB

  const int t = threadIdx.x;
  const int wave = t >> 6, lane = t & 63;
  const int wm = wave >> 2;        // 2 M-halves
  const int wn = wave & 3;         // 4 N-quarters

  int flat = blockIdx.y * 4 + blockIdx.x;
  flat = (flat & 7) * 64 + (flat >> 3);
  const int tileN = (flat & 3) * 256;
  const int tileM = (flat >> 2) * 256;

  // staging geometry: flat8 = i*512 + t -> (row 0..255, slot 0..7 of 16B)
  int rowS_[4], gsS_[4], ldsS_[4];
#pragma unroll
  for (int i = 0; i < 4; ++i) {
    const int f8 = i * 512 + t;
    rowS_[i] = f8 >> 3;
    const int slot = f8 & 7;
    gsS_[i] = slot ^ (rowS_[i] & 7);           // pre-swizzled source slot
    ldsS_[i] = (i * 512 + wave * 64) * 8;      // wave-uniform elem base
  }

  const int fr = lane & 15;
  const int sc = lane >> 4;       // 0..3

  auto stageAB = [&](int buf, int k0) {
#pragma unroll
    for (int i = 0; i < 4; ++i) {
      const size_t ga = (size_t)(tileM + rowS_[i]) * 1024 + k0 + gsS_[i] * 8;
      g2l16(probs + ga, &Asd[buf * 16384 + ldsS_[i]]);
      const size_t gb = (size_t)(tileN + rowS_[i]) * 1024 + k0 + gsS_[i] * 8;
      g2l16(memT + gb, &Bsd[buf * 16384 + ldsS_[i]]);
    }
  };

  f32x4 acc[8][4] = {};

  // prologue: stage super-tile 0 into buffer 0
  stageAB(0, 0);
  asm volatile("s_waitcnt vmcnt(0)" ::: "memory");
  __builtin_amdgcn_s_barrier();

  for (int st = 0; st < 16; ++st) {
    const int buf = st & 1, nxt = buf ^ 1;
    const char* Ab = (const char*)Asd + buf * 32768;
    const char* Bb = (const char*)Bsd + buf * 32768;
#pragma unroll
    for (int kk = 0; kk < 2; ++kk) {
      half8 a[4], b[4];
      // ---- Pa: read A m0-3 + B n0-3 (kk); (kk0) issue next stage
#pragma unroll
      for (int mf = 0; mf < 4; ++mf) {
        const int row = wm * 128 + mf * 16 + fr;
        a[mf] = *(const half8*)(Ab + row * 128 + (((kk * 4 + sc) ^ (fr & 7)) << 4));
      }
#pragma unroll
      for (int nf = 0; nf < 4; ++nf) {
        const int row = wn * 64 + nf * 16 + fr;
        b[nf] = *(const half8*)(Bb + row * 128 + (((kk * 4 + sc) ^ (fr & 7)) << 4));
      }
      if (kk == 0 && st < 15) stageAB(nxt, (st + 1) * 64);
      __builtin_amdgcn_s_barrier();
      __builtin_amdgcn_s_setprio(1);
#pragma unroll
      for (int mf = 0; mf < 4; ++mf)
#pragma unroll
        for (int nf = 0; nf < 4; ++nf)
          acc[mf][nf] = __builtin_amdgcn_mfma_f32_16x16x32_f16(a[mf], b[nf], acc[mf][nf], 0, 0, 0);
      __builtin_amdgcn_s_setprio(0);
      __builtin_amdgcn_s_barrier();

      // ---- Pb: read A m4-7 (kk); MFMA m4-7 x n0-3
#pragma unroll
      for (int mf = 0; mf < 4; ++mf) {
        const int row = wm * 128 + (4 + mf) * 16 + fr;
        a[mf] = *(const half8*)(Ab + row * 128 + (((kk * 4 + sc) ^ (fr & 7)) << 4));
      }
      __builtin_amdgcn_s_barrier();
      __builtin_amdgcn_s_setprio(1);
#pragma unroll
      for (int mf = 0; mf < 4; ++mf)
#pragma unroll
        for (int nf = 0; nf < 4; ++nf)
          acc[4 + mf][nf] = __builtin_amdgcn_mfma_f32_16x16x32_f16(a[mf], b[nf], acc[4 + mf][nf], 0, 0, 0);
      __builtin_amdgcn_s_setprio(0);
      if (kk == 1 && st < 15)
        asm volatile("s_waitcnt vmcnt(0)" ::: "memory");  // next stage done (7 phases old)
      __builtin_amdgcn_s_barrier();
    }
  }

  // epilogue: C/D layout col = lane&15, row = (lane>>4)*4 + reg
  const int er = (lane >> 4) * 4;
  const int ec = lane & 15;
#pragma unroll
  for (int nf = 0; nf < 4; ++nf) {
    const int col = tileN + wn * 64 + nf * 16 + ec;
#pragma unroll
    for (int mf = 0; mf < 8; ++mf) {
#pragma unroll
      for (int r = 0; r < 4; ++r) {
        const int row = tileM + wm * 128 + mf * 16 + er + r;
        Of[(size_t)row * 1024 + col] = acc[mf][nf][r];
      }
    }
  }
}

// ---------------------------------------------------------------------------
extern "C" void kernel_launch(void* const* d_in, const int* in_sizes, int n_in,
                              void* d_out, int out_size, void* d_ws, size_t ws_size,
                              hipStream_t stream) {
  const float* x   = (const float*)d_in[0];   // [32768][1024]
  const float* W   = (const float*)d_in[1];   // [1024][1024]  (out=e, in=d)
  const float* b   = (const float*)d_in[2];   // [1024]
  const float* mem = (const float*)d_in[3];   // [1024][1024]  (m, e)
  float* out = (float*)d_out;

  char* ws = (char*)d_ws;
  const size_t MB = 1024 * 1024;
  float*    attn  = (float*)(ws);              // 128 MB
  _Float16* probs = (_Float16*)(ws + 128 * MB);// 64 MB
  __bf16*   Mh    = (__bf16*)(ws + 192 * MB);  // 2 MB
  __bf16*   Ml    = (__bf16*)(ws + 194 * MB);  // 2 MB
  __bf16*   Wth   = (__bf16*)(ws + 196 * MB);  // 2 MB
  __bf16*   Wtl   = (__bf16*)(ws + 198 * MB);  // 2 MB
  __bf16*   Ph    = (__bf16*)(ws + 200 * MB);  // 2 MB
  __bf16*   Pl    = (__bf16*)(ws + 202 * MB);  // 2 MB
  _Float16* memT  = (_Float16*)(ws + 204 * MB);// 2 MB
  float*    cvec  = (float*)(ws + 206 * MB);   // 4 KB

  // preps (all tiny)
  split_mem<<<4096, 256, 0, stream>>>(mem, Mh, Ml);
  transpose_split_W<<<dim3(32, 32), dim3(32, 8), 0, stream>>>(W, Wth, Wtl);
  transpose_mem<<<dim3(32, 32), dim3(32, 8), 0, stream>>>(mem, memT);
  bias_c<<<256, 256, 0, stream>>>(b, mem, cvec);

  // P = mem @ W  (split-bf16, out split bf16)
  gemm_p<<<dim3(8, 8), 256, 0, stream>>>(Mh, Ml, Wth, Wtl, Ph, Pl);

  // attn = x @ P^T + c  (256x256 4-phase, counted-vmcnt pipeline)
  gemm_attn_8ph<<<dim3(4, 128), 512, 0, stream>>>(x, Ph, Pl, cvec, attn);

  // softmax -> fp16 probs
  softmax_k<<<32768, 256, 0, stream>>>(attn, probs);

  // context = probs @ mem  (256x256 4-phase fp16 tiled GEMM)
  gemm_ctx<<<dim3(4, 128), 512, 0, stream>>>(probs, memT, out);
}

// Round 8
// 547.459 us; speedup vs baseline: 1.1535x; 1.1535x over previous
//
#include <hip/hip_runtime.h>
#include <hip/hip_bf16.h>
#include <hip/hip_fp16.h>

// Problem dims (hard-coded): B=8, S=4096, DIM=1024, M=1024
// Algebraic restructure: attn = x @ (mem·W)^T + (mem·b); softmax; out = probs @ mem
// Round 8: revert gemm_attn to the r6 version (253 us best) and the tail to
// the r5 fused kernel, upgraded to 64 rows/block (512 blocks, 128 KB P-tile):
// halves the per-CU memTb L2 traffic (2 GB -> 1 GB), the hypothesized limiter.
#define KDIM 1024

typedef __attribute__((ext_vector_type(8))) __bf16    bf16x8;
typedef __attribute__((ext_vector_type(4))) __bf16    bf16x4;
typedef __attribute__((ext_vector_type(8))) _Float16  half8;
typedef __attribute__((ext_vector_type(4))) _Float16  half4v;
typedef __attribute__((ext_vector_type(4))) float     f32x4;

// async global->LDS, 16B per lane. LDS base must be wave-uniform; HW adds lane*16.
__device__ __forceinline__ void g2l16(const void* g, void* l) {
  __builtin_amdgcn_global_load_lds(
      (const __attribute__((address_space(1))) unsigned int*)g,
      (__attribute__((address_space(3))) unsigned int*)l, 16, 0, 0);
}

__device__ __forceinline__ void split2(float v, __bf16& h, __bf16& l) {
  h = (__bf16)v;
  l = (__bf16)(v - (float)h);
}

// ---------------------------------------------------------------------------
// split mem into bf16 hi/lo (row-major [m][e], already B^T/A layout for P-GEMM)
__global__ __launch_bounds__(256) void split_mem(
    const float* __restrict__ mem, __bf16* __restrict__ Mh, __bf16* __restrict__ Ml) {
  int i = blockIdx.x * 256 + threadIdx.x;   // 1M threads
  __bf16 h, l;
  split2(mem[i], h, l);
  Mh[i] = h; Ml[i] = l;
}

// transpose W [e][d] -> Wt [d][e], split to bf16 hi/lo (B^T layout for P-GEMM)
__global__ __launch_bounds__(256) void transpose_split_W(
    const float* __restrict__ W, __bf16* __restrict__ Wth, __bf16* __restrict__ Wtl) {
  __shared__ float tl[32][33];
  int bx = blockIdx.x, by = blockIdx.y;
  int tx = threadIdx.x, ty = threadIdx.y;   // (32, 8)
#pragma unroll
  for (int j = 0; j < 4; ++j)
    tl[ty + 8 * j][tx] = W[(by * 32 + ty + 8 * j) * 1024 + bx * 32 + tx];
  __syncthreads();
#pragma unroll
  for (int j = 0; j < 4; ++j) {
    float v = tl[tx][ty + 8 * j];
    __bf16 h, l;
    split2(v, h, l);
    const int idx = (bx * 32 + ty + 8 * j) * 1024 + by * 32 + tx;
    Wth[idx] = h; Wtl[idx] = l;
  }
}

// mem [m][e] fp32 -> memTb fp16 packed in MFMA B-fragment lane order.
// Fragment f = nt*32 + kt; entry (lane l, j):
//   value = (fp16) mem[kt*32 + (l>>4)*8 + j][nt*16 + (l&15)]
//   byte offset = f*1024 + l*16 + j*2
__global__ __launch_bounds__(256) void build_memTb(
    const float* __restrict__ mem, _Float16* __restrict__ memTb) {
  const int id = blockIdx.x * 256 + threadIdx.x;   // 131072 threads
  const int l  = id & 63;
  const int f  = id >> 6;        // 0..2047
  const int kt = f & 31;
  const int nt = f >> 5;
  const int n  = nt * 16 + (l & 15);
  const int k0 = kt * 32 + (l >> 4) * 8;
  half8 o;
#pragma unroll
  for (int j = 0; j < 8; ++j)
    o[j] = (_Float16)mem[(size_t)(k0 + j) * 1024 + n];
  *(half8*)(memTb + (size_t)id * 8) = o;
}

// c[m] = sum_e b[e] * mem[m][e]  (fp32). One wave per row.
__global__ __launch_bounds__(256) void bias_c(
    const float* __restrict__ b, const float* __restrict__ mem,
    float* __restrict__ c) {
  const int wave = threadIdx.x >> 6, lane = threadIdx.x & 63;
  const int row = blockIdx.x * 4 + wave;
  float s = 0.f;
#pragma unroll
  for (int j = 0; j < 16; ++j) {
    const int e = lane + 64 * j;
    s += b[e] * mem[row * 1024 + e];
  }
#pragma unroll
  for (int off = 32; off; off >>= 1) s += __shfl_xor(s, off);
  if (lane == 0) c[row] = s;
}

// ---------------------------------------------------------------------------
// Split-bf16 compensated GEMM for the small P = mem @ W product
// (128x128 tile, known-good structure). Epilogue writes C as bf16 hi/lo.
__global__ __launch_bounds__(256) void gemm_p(
    const __bf16* __restrict__ Agh, const __bf16* __restrict__ Agl,
    const __bf16* __restrict__ Bgh, const __bf16* __restrict__ Bgl,
    __bf16* __restrict__ Oh, __bf16* __restrict__ Ol) {
  __shared__ __attribute__((aligned(16))) __bf16 Ah[128 * 32];
  __shared__ __attribute__((aligned(16))) __bf16 Al[128 * 32];
  __shared__ __attribute__((aligned(16))) __bf16 Bh[128 * 32];
  __shared__ __attribute__((aligned(16))) __bf16 Bl[128 * 32];

  const int t = threadIdx.x;
  const int wave = t >> 6;
  const int lane = t & 63;
  const int wm = wave & 1, wn = wave >> 1;

  const int nwg = gridDim.x * gridDim.y;
  int flat = blockIdx.y * gridDim.x + blockIdx.x;
  if ((nwg & 7) == 0) {
    const int cpx = nwg >> 3;
    flat = (flat & 7) * cpx + (flat >> 3);
  }
  const int tileN = (flat % gridDim.x) * 128;
  const int tileM = (flat / gridDim.x) * 128;

  f32x4 acc[4][4] = {};

  const int rS = lane >> 2;
  const int cS = (lane & 3) * 8;

  for (int kt = 0; kt < KDIM / 32; ++kt) {
    const int k0 = kt * 32;
    __syncthreads();
#pragma unroll
    for (int i = 0; i < 2; ++i) {
      const int rb = i * 64 + wave * 16;
      const int grb = (tileN + rb + rS) * KDIM + k0 + cS;
      g2l16(Bgh + grb, &Bh[rb * 32]);
      g2l16(Bgl + grb, &Bl[rb * 32]);
      const int gra = (tileM + rb + rS) * KDIM + k0 + cS;
      g2l16(Agh + gra, &Ah[rb * 32]);
      g2l16(Agl + gra, &Al[rb * 32]);
    }
    __syncthreads();

    const int fr = lane & 15;
    const int fk = (lane >> 4) * 8;
    bf16x8 afh[4], afl[4], bfh[4], bfl[4];
#pragma unroll
    for (int mf = 0; mf < 4; ++mf) {
      const int r = wm * 64 + mf * 16 + fr;
      afh[mf] = *(const bf16x8*)(&Ah[r * 32 + fk]);
      afl[mf] = *(const bf16x8*)(&Al[r * 32 + fk]);
    }
#pragma unroll
    for (int nf = 0; nf < 4; ++nf) {
      const int r = wn * 64 + nf * 16 + fr;
      bfh[nf] = *(const bf16x8*)(&Bh[r * 32 + fk]);
      bfl[nf] = *(const bf16x8*)(&Bl[r * 32 + fk]);
    }
#pragma unroll
    for (int mf = 0; mf < 4; ++mf)
#pragma unroll
      for (int nf = 0; nf < 4; ++nf) {
        acc[mf][nf] = __builtin_amdgcn_mfma_f32_16x16x32_bf16(afh[mf], bfh[nf], acc[mf][nf], 0, 0, 0);
        acc[mf][nf] = __builtin_amdgcn_mfma_f32_16x16x32_bf16(afh[mf], bfl[nf], acc[mf][nf], 0, 0, 0);
        acc[mf][nf] = __builtin_amdgcn_mfma_f32_16x16x32_bf16(afl[mf], bfh[nf], acc[mf][nf], 0, 0, 0);
      }
  }

  const int er = (lane >> 4) * 4;
  const int ec = lane & 15;
#pragma unroll
  for (int nf = 0; nf < 4; ++nf) {
    const int col = tileN + wn * 64 + nf * 16 + ec;
#pragma unroll
    for (int mf = 0; mf < 4; ++mf) {
#pragma unroll
      for (int r = 0; r < 4; ++r) {
        const int row = tileM + wm * 64 + mf * 16 + er + r;
        const size_t idx = (size_t)row * KDIM + col;
        float v = acc[mf][nf][r];
        __bf16 h = (__bf16)v;
        Oh[idx] = h;
        Ol[idx] = (__bf16)(v - (float)h);
      }
    }
  }
}

// ---------------------------------------------------------------------------
// attn = x @ P^T + c : 256x256 tile, BK=32, 8 waves, 4 quadrant-phases/K-tile.
// EXACT round-6 version (best measured: 253 us, MfmaUtil 34, 0 bank conflicts).
__global__ __launch_bounds__(512, 2) void gemm_attn_8ph(
    const float* __restrict__ X,
    const __bf16* __restrict__ Pgh, const __bf16* __restrict__ Pgl,
    const float* __restrict__ bias,
    float* __restrict__ Of) {
  __shared__ __attribute__((aligned(16))) __bf16 AhL[2 * 8192];
  __shared__ __attribute__((aligned(16))) __bf16 AlL[2 * 8192];
  __shared__ __attribute__((aligned(16))) __bf16 BhL[2 * 8192];
  __shared__ __attribute__((aligned(16))) __bf16 BlL[2 * 8192];

  const int t = threadIdx.x;
  const int wave = t >> 6, lane = t & 63;
  const int wm = wave >> 2;        // 2 M-halves (128 rows each)
  const int wn = wave & 3;         // 4 N-quarters (64 cols each)

  // XCD-aware bijective remap; nwg = 4*128 = 512
  int flat = blockIdx.y * 4 + blockIdx.x;
  flat = (flat & 7) * 64 + (flat >> 3);
  const int tileN = (flat & 3) * 256;
  const int tileM = (flat >> 2) * 256;

  // ---- staging geometry
  int rowB_[2], gsB_[2], ldsB_[2];
#pragma unroll
  for (int i = 0; i < 2; ++i) {
    const int f16 = i * 512 + t;
    rowB_[i] = f16 >> 2;
    const int slot = f16 & 3;
    gsB_[i] = slot ^ ((rowB_[i] >> 1) & 3);       // pre-swizzled src col group
    ldsB_[i] = (i * 512 + wave * 64) * 8;         // wave-uniform elem base
  }
  int rowA_[4], colA_[4], physA_[4];
#pragma unroll
  for (int i = 0; i < 4; ++i) {
    const int f4 = i * 512 + t;
    rowA_[i] = f4 >> 3;
    const int col8 = f4 & 7;
    colA_[i] = col8 * 4;
    physA_[i] = rowA_[i] * 64 +
                ((((col8 >> 1) ^ ((rowA_[i] >> 1) & 3)) << 4)) + (col8 & 1) * 8;
  }

  const int fr = lane & 15;
  const int sc = lane >> 4;
  const int swF = (fr >> 1) & 3;
  const int fragoff = ((sc ^ swF) << 4);

  f32x4 acc[8][4] = {};
  f32x4 xr[4];

  auto xload = [&](int k0) {
#pragma unroll
    for (int i = 0; i < 4; ++i)
      xr[i] = *(const f32x4*)(X + (size_t)(tileM + rowA_[i]) * 1024 + k0 + colA_[i]);
  };
  auto stageB = [&](int buf, int k0) {
#pragma unroll
    for (int i = 0; i < 2; ++i) {
      const size_t g = (size_t)(tileN + rowB_[i]) * 1024 + k0 + gsB_[i] * 8;
      g2l16(Pgh + g, &BhL[buf * 8192 + ldsB_[i]]);
      g2l16(Pgl + g, &BlL[buf * 8192 + ldsB_[i]]);
    }
  };
  auto xwrite = [&](int buf) {
#pragma unroll
    for (int i = 0; i < 4; ++i) {
      bf16x4 h, l;
#pragma unroll
      for (int j = 0; j < 4; ++j) {
        const float vj = xr[i][j];
        __bf16 hh = (__bf16)vj;
        h[j] = hh;
        l[j] = (__bf16)(vj - (float)hh);
      }
      *(bf16x4*)((char*)AhL + buf * 16384 + physA_[i]) = h;
      *(bf16x4*)((char*)AlL + buf * 16384 + physA_[i]) = l;
    }
  };
  auto mm3 = [&](f32x4& a, const bf16x8& ah, const bf16x8& al,
                 const bf16x8& bh, const bf16x8& bl) {
    a = __builtin_amdgcn_mfma_f32_16x16x32_bf16(ah, bh, a, 0, 0, 0);
    a = __builtin_amdgcn_mfma_f32_16x16x32_bf16(ah, bl, a, 0, 0, 0);
    a = __builtin_amdgcn_mfma_f32_16x16x32_bf16(al, bh, a, 0, 0, 0);
  };

  // ---- prologue: stage K-tile 0 into buffer 0
  xload(0);
  stageB(0, 0);
  xwrite(0);   // compiler emits counted vmcnt for xr before the splits
  asm volatile("s_waitcnt vmcnt(0) lgkmcnt(0)" ::: "memory");
  __builtin_amdgcn_s_barrier();

  int cur = 0;
  for (int kt = 0; kt < 32; ++kt) {
    const int nxt = cur ^ 1;
    const int k1 = (kt + 1) * 32;
    bf16x8 ah[4], al[4], b0h[2], b0l[2], b1h[2], b1l[2];

    // ---- P0: read A m0-3 + B n0-1; issue next-tile x loads + B g2l16
#pragma unroll
    for (int mf = 0; mf < 4; ++mf) {
      const int row = wm * 128 + mf * 16 + fr;
      const int off = cur * 16384 + row * 64 + fragoff;
      ah[mf] = *(const bf16x8*)((const char*)AhL + off);
      al[mf] = *(const bf16x8*)((const char*)AlL + off);
    }
#pragma unroll
    for (int nf = 0; nf < 2; ++nf) {
      const int row = wn * 64 + nf * 16 + fr;
      const int off = cur * 16384 + row * 64 + fragoff;
      b0h[nf] = *(const bf16x8*)((const char*)BhL + off);
      b0l[nf] = *(const bf16x8*)((const char*)BlL + off);
    }
    if (kt < 31) { xload(k1); stageB(nxt, k1); }
    __builtin_amdgcn_s_barrier();
    __builtin_amdgcn_s_setprio(1);
#pragma unroll
    for (int mf = 0; mf < 4; ++mf)
#pragma unroll
      for (int nf = 0; nf < 2; ++nf)
        mm3(acc[mf][nf], ah[mf], al[mf], b0h[nf], b0l[nf]);
    __builtin_amdgcn_s_setprio(0);
    __builtin_amdgcn_s_barrier();

    // ---- P1: read B n2-3; MFMA m0-3 x n2-3
#pragma unroll
    for (int nf = 0; nf < 2; ++nf) {
      const int row = wn * 64 + (2 + nf) * 16 + fr;
      const int off = cur * 16384 + row * 64 + fragoff;
      b1h[nf] = *(const bf16x8*)((const char*)BhL + off);
      b1l[nf] = *(const bf16x8*)((const char*)BlL + off);
    }
    __builtin_amdgcn_s_barrier();
    __builtin_amdgcn_s_setprio(1);
#pragma unroll
    for (int mf = 0; mf < 4; ++mf)
#pragma unroll
      for (int nf = 0; nf < 2; ++nf)
        mm3(acc[mf][2 + nf], ah[mf], al[mf], b1h[nf], b1l[nf]);
    __builtin_amdgcn_s_setprio(0);
    __builtin_amdgcn_s_barrier();

    // ---- P2: read A m4-7; split+write next-tile A; MFMA m4-7 x n0-1
#pragma unroll
    for (int mf = 0; mf < 4; ++mf) {
      const int row = wm * 128 + (4 + mf) * 16 + fr;
      const int off = cur * 16384 + row * 64 + fragoff;
      ah[mf] = *(const bf16x8*)((const char*)AhL + off);
      al[mf] = *(const bf16x8*)((const char*)AlL + off);
    }
    if (kt < 31) xwrite(nxt);   // auto vmcnt(4): waits x loads, B stays in flight
    __builtin_amdgcn_s_barrier();
    __builtin_amdgcn_s_setprio(1);
#pragma unroll
    for (int mf = 0; mf < 4; ++mf)
#pragma unroll
      for (int nf = 0; nf < 2; ++nf)
        mm3(acc[4 + mf][nf], ah[mf], al[mf], b0h[nf], b0l[nf]);
    __builtin_amdgcn_s_setprio(0);
    __builtin_amdgcn_s_barrier();

    // ---- P3: MFMA m4-7 x n2-3; tile-end drain (ops are >=2 phases old)
    __builtin_amdgcn_s_setprio(1);
#pragma unroll
    for (int mf = 0; mf < 4; ++mf)
#pragma unroll
      for (int nf = 0; nf < 2; ++nf)
        mm3(acc[4 + mf][2 + nf], ah[mf], al[mf], b1h[nf], b1l[nf]);
    __builtin_amdgcn_s_setprio(0);
    asm volatile("s_waitcnt vmcnt(0) lgkmcnt(0)" ::: "memory");
    __builtin_amdgcn_s_barrier();
    cur = nxt;
  }

  // ---- epilogue: C/D layout col = lane&15, row = (lane>>4)*4 + reg; + bias
  const int er = (lane >> 4) * 4;
  const int ec = lane & 15;
#pragma unroll
  for (int nf = 0; nf < 4; ++nf) {
    const int col = tileN + wn * 64 + nf * 16 + ec;
    const float bv = bias[col];
#pragma unroll
    for (int mf = 0; mf < 8; ++mf) {
#pragma unroll
      for (int r = 0; r < 4; ++r) {
        const int row = tileM + wm * 128 + mf * 16 + er + r;
        Of[(size_t)row * 1024 + col] = acc[mf][nf][r] + bv;
      }
    }
  }
}

// ---------------------------------------------------------------------------
// Fused softmax + context GEMM, 64 rows/block (512 blocks, 512 threads).
// Each b-fragment read from memTb now feeds 64 MFMAs (2 row-groups of 32)
// instead of 32 -> memTb L2 traffic halved (2 GB -> 1 GB), attacking the
// per-CU L2-read-throughput limit that capped the 32-row version at ~250 us.
// Per-row softmax and per-element accumulation order identical to r5.
__global__ __launch_bounds__(512, 2) void fused_softmax_ctx64(
    const float* __restrict__ attn, const _Float16* __restrict__ memTb,
    float* __restrict__ out) {
  __shared__ __attribute__((aligned(16))) _Float16 P[64 * 1024];  // 128 KB

  const int t = threadIdx.x;
  const int wave = t >> 6, lane = t & 63;
  const int riw = lane >> 4;       // row within wave's 4-row group
  const int cg = lane & 15;        // col group (16 threads per row)
  const size_t grow0 = (size_t)blockIdx.x * 64;

  // B fragments for this wave: nt = wave*8 + nf; fragment (nf, kt) at
  // bb + (nf*32 + kt)*1024 bytes; lane's 16B slice at +lane*16.
  const char* bb = (const char*)memTb + (size_t)(wave * 256) * 1024 + lane * 16;

  // --- softmax: two passes of 32 rows (rows p*32 + wave*4 + riw)
#pragma unroll
  for (int p = 0; p < 2; ++p) {
    const int row = p * 32 + wave * 4 + riw;
    f32x4 v[16];
    {
      const f32x4* arow = (const f32x4*)(attn + (grow0 + row) * 1024);
#pragma unroll
      for (int j = 0; j < 16; ++j) v[j] = arow[cg + j * 16];
    }
    float m = -1e30f;
#pragma unroll
    for (int j = 0; j < 16; ++j)
      m = fmaxf(m, fmaxf(fmaxf(v[j].x, v[j].y), fmaxf(v[j].z, v[j].w)));
#pragma unroll
    for (int off = 1; off < 16; off <<= 1) m = fmaxf(m, __shfl_xor(m, off));

    float s = 0.f;
#pragma unroll
    for (int j = 0; j < 16; ++j) {
      v[j].x = expf(v[j].x - m);
      v[j].y = expf(v[j].y - m);
      v[j].z = expf(v[j].z - m);
      v[j].w = expf(v[j].w - m);
      s += (v[j].x + v[j].y) + (v[j].z + v[j].w);
    }
#pragma unroll
    for (int off = 1; off < 16; off <<= 1) s += __shfl_xor(s, off);
    const float inv = 1.0f / s;

    const int swz = (row & 7) << 4;
    char* rbase = (char*)P + row * 2048;
#pragma unroll
    for (int j = 0; j < 16; ++j) {
      half4v o;
      o[0] = (_Float16)(v[j].x * inv);
      o[1] = (_Float16)(v[j].y * inv);
      o[2] = (_Float16)(v[j].z * inv);
      o[3] = (_Float16)(v[j].w * inv);
      const int byteoff = (cg * 8 + j * 128) ^ swz;   // 8B-aligned, bijective
      *(half4v*)(rbase + byteoff) = o;
    }
  }

  // prefetch B-frags for kt=0 and kt=1 (stay in flight across the barrier)
  half8 b0[8], b1[8];
#pragma unroll
  for (int nf = 0; nf < 8; ++nf)
    b0[nf] = *(const half8*)(bb + nf * 32768);
#pragma unroll
  for (int nf = 0; nf < 8; ++nf)
    b1[nf] = *(const half8*)(bb + nf * 32768 + 1024);

  __syncthreads();

  // --- context GEMM: out[64 rows][wave's 128 cols] = P @ mem
  // Depth-2 pipeline on B; each b-set feeds 4 row-group MFMAs (64 MFMA).
  const int fr = lane & 15;
  const int fko = (lane >> 4) * 8;   // k element offset within 32
  f32x4 acc[4][8] = {};

  for (int kt = 0; kt < 32; kt += 2) {
    // ---- step A: kt, uses b0
    {
      half8 a[4];
#pragma unroll
      for (int mf = 0; mf < 4; ++mf) {
        const int ar = mf * 16 + fr;
        const int kbyte = ((kt * 32 + fko) * 2) ^ ((ar & 7) << 4);
        a[mf] = *(const half8*)((const char*)P + ar * 2048 + kbyte);
      }
#pragma unroll
      for (int mf = 0; mf < 4; ++mf)
#pragma unroll
        for (int nf = 0; nf < 8; ++nf)
          acc[mf][nf] = __builtin_amdgcn_mfma_f32_16x16x32_f16(a[mf], b0[nf], acc[mf][nf], 0, 0, 0);
      if (kt + 2 < 32) {
#pragma unroll
        for (int nf = 0; nf < 8; ++nf)
          b0[nf] = *(const half8*)(bb + nf * 32768 + (kt + 2) * 1024);
      }
    }
    // ---- step B: kt+1, uses b1
    {
      half8 a[4];
#pragma unroll
      for (int mf = 0; mf < 4; ++mf) {
        const int ar = mf * 16 + fr;
        const int kbyte = (((kt + 1) * 32 + fko) * 2) ^ ((ar & 7) << 4);
        a[mf] = *(const half8*)((const char*)P + ar * 2048 + kbyte);
      }
#pragma unroll
      for (int mf = 0; mf < 4; ++mf)
#pragma unroll
        for (int nf = 0; nf < 8; ++nf)
          acc[mf][nf] = __builtin_amdgcn_mfma_f32_16x16x32_f16(a[mf], b1[nf], acc[mf][nf], 0, 0, 0);
      if (kt + 3 < 32) {
#pragma unroll
        for (int nf = 0; nf < 8; ++nf)
          b1[nf] = *(const half8*)(bb + nf * 32768 + (kt + 3) * 1024);
      }
    }
  }

  // --- epilogue. C/D layout: col = lane&15, row = (lane>>4)*4 + reg
  const int colbase = wave * 128;
  const int er = (lane >> 4) * 4;
  const int ec = lane & 15;
#pragma unroll
  for (int mf = 0; mf < 4; ++mf)
#pragma unroll
    for (int nf = 0; nf < 8; ++nf) {
      const int col = colbase + nf * 16 + ec;
#pragma unroll
      for (int r = 0; r < 4; ++r)
        out[(grow0 + mf * 16 + er + r) * 1024 + col] = acc[mf][nf][r];
    }
}

// ---------------------------------------------------------------------------
extern "C" void kernel_launch(void* const* d_in, const int* in_sizes, int n_in,
                              void* d_out, int out_size, void* d_ws, size_t ws_size,
                              hipStream_t stream) {
  const float* x   = (const float*)d_in[0];   // [32768][1024]
  const float* W   = (const float*)d_in[1];   // [1024][1024]  (out=e, in=d)
  const float* b   = (const float*)d_in[2];   // [1024]
  const float* mem = (const float*)d_in[3];   // [1024][1024]  (m, e)
  float* out = (float*)d_out;

  char* ws = (char*)d_ws;
  const size_t MB = 1024 * 1024;
  float*    attn  = (float*)(ws);              // 128 MB
  __bf16*   Mh    = (__bf16*)(ws + 192 * MB);  // 2 MB
  __bf16*   Ml    = (__bf16*)(ws + 194 * MB);  // 2 MB
  __bf16*   Wth   = (__bf16*)(ws + 196 * MB);  // 2 MB
  __bf16*   Wtl   = (__bf16*)(ws + 198 * MB);  // 2 MB
  __bf16*   Ph    = (__bf16*)(ws + 200 * MB);  // 2 MB
  __bf16*   Pl    = (__bf16*)(ws + 202 * MB);  // 2 MB
  _Float16* memTb = (_Float16*)(ws + 204 * MB);// 2 MB
  float*    cvec  = (float*)(ws + 206 * MB);   // 4 KB

  // preps (all tiny)
  split_mem<<<4096, 256, 0, stream>>>(mem, Mh, Ml);
  transpose_split_W<<<dim3(32, 32), dim3(32, 8), 0, stream>>>(W, Wth, Wtl);
  build_memTb<<<512, 256, 0, stream>>>(mem, memTb);
  bias_c<<<256, 256, 0, stream>>>(b, mem, cvec);

  // P = mem @ W  (split-bf16, out split bf16)
  gemm_p<<<dim3(8, 8), 256, 0, stream>>>(Mh, Ml, Wth, Wtl, Ph, Pl);

  // attn = x @ P^T + c  (r6 256x256 4-phase, 253 us known-good)
  gemm_attn_8ph<<<dim3(4, 128), 512, 0, stream>>>(x, Ph, Pl, cvec, attn);

  // fused softmax + context = probs @ mem  (64 rows/block, halved B-traffic)
  fused_softmax_ctx64<<<512, 512, 0, stream>>>(attn, memTb, out);
}

// Round 9
// 543.536 us; speedup vs baseline: 1.1618x; 1.0072x over previous
//
#include <hip/hip_runtime.h>
#include <hip/hip_bf16.h>
#include <hip/hip_fp16.h>

// Problem dims (hard-coded): B=8, S=4096, DIM=1024, M=1024
// Algebraic restructure: attn = x @ (mem·W)^T + (mem·b); softmax; out = probs @ mem
// Round 9: (1) fused64's B pipeline deepened to 3 (reload kt+3 after consuming
// kt -> 2-step latency cover >= L2 latency; it was 1 step at depth-2);
// (2) build_memTb rewritten with coalesced LDS-tiled transpose (old version
// did 8 scalar 4-B strided reads/thread). gemm_attn untouched (252 us proven).
#define KDIM 1024

typedef __attribute__((ext_vector_type(8))) __bf16    bf16x8;
typedef __attribute__((ext_vector_type(4))) __bf16    bf16x4;
typedef __attribute__((ext_vector_type(8))) _Float16  half8;
typedef __attribute__((ext_vector_type(4))) _Float16  half4v;
typedef __attribute__((ext_vector_type(4))) float     f32x4;

// async global->LDS, 16B per lane. LDS base must be wave-uniform; HW adds lane*16.
__device__ __forceinline__ void g2l16(const void* g, void* l) {
  __builtin_amdgcn_global_load_lds(
      (const __attribute__((address_space(1))) unsigned int*)g,
      (__attribute__((address_space(3))) unsigned int*)l, 16, 0, 0);
}

__device__ __forceinline__ void split2(float v, __bf16& h, __bf16& l) {
  h = (__bf16)v;
  l = (__bf16)(v - (float)h);
}

// ---------------------------------------------------------------------------
// split mem into bf16 hi/lo (row-major [m][e], already B^T/A layout for P-GEMM)
__global__ __launch_bounds__(256) void split_mem(
    const float* __restrict__ mem, __bf16* __restrict__ Mh, __bf16* __restrict__ Ml) {
  int i = blockIdx.x * 256 + threadIdx.x;   // 1M threads
  __bf16 h, l;
  split2(mem[i], h, l);
  Mh[i] = h; Ml[i] = l;
}

// transpose W [e][d] -> Wt [d][e], split to bf16 hi/lo (B^T layout for P-GEMM)
__global__ __launch_bounds__(256) void transpose_split_W(
    const float* __restrict__ W, __bf16* __restrict__ Wth, __bf16* __restrict__ Wtl) {
  __shared__ float tl[32][33];
  int bx = blockIdx.x, by = blockIdx.y;
  int tx = threadIdx.x, ty = threadIdx.y;   // (32, 8)
#pragma unroll
  for (int j = 0; j < 4; ++j)
    tl[ty + 8 * j][tx] = W[(by * 32 + ty + 8 * j) * 1024 + bx * 32 + tx];
  __syncthreads();
#pragma unroll
  for (int j = 0; j < 4; ++j) {
    float v = tl[tx][ty + 8 * j];
    __bf16 h, l;
    split2(v, h, l);
    const int idx = (bx * 32 + ty + 8 * j) * 1024 + by * 32 + tx;
    Wth[idx] = h; Wtl[idx] = l;
  }
}

// mem [m][e] fp32 -> memTb fp16 packed in MFMA B-fragment lane order.
// Fragment f = nt*32 + kt; entry (lane l, j):
//   value = (fp16) mem[kt*32 + (l>>4)*8 + j][nt*16 + (l&15)]
//   byte offset = f*1024 + l*16 + j*2
// Coalesced: block (kt, ct) stages mem rows kt*32..+31, cols ct*64..+63 in an
// LDS tile (coalesced float4 reads), then each thread emits one 16-B lane
// slice (contiguous, coalesced). Output bit-identical to the old kernel.
__global__ __launch_bounds__(256) void build_memTb(
    const float* __restrict__ mem, _Float16* __restrict__ memTb) {
  __shared__ float tile[32][65];
  const int t = threadIdx.x;
  const int kt = blockIdx.x >> 4;       // 0..31
  const int ct = blockIdx.x & 15;       // 0..15 (64-col group)
  // load: 32 rows x 64 cols fp32, coalesced
  {
    const int r = t >> 3;
    const int c = (t & 7) * 8;
    const float4 v0 = *(const float4*)(mem + (size_t)(kt * 32 + r) * 1024 + ct * 64 + c);
    const float4 v1 = *(const float4*)(mem + (size_t)(kt * 32 + r) * 1024 + ct * 64 + c + 4);
    tile[r][c + 0] = v0.x; tile[r][c + 1] = v0.y; tile[r][c + 2] = v0.z; tile[r][c + 3] = v0.w;
    tile[r][c + 4] = v1.x; tile[r][c + 5] = v1.y; tile[r][c + 6] = v1.z; tile[r][c + 7] = v1.w;
  }
  __syncthreads();
  // emit: thread -> (local frag ntl = t>>6, lane l = t&63), one half8 slice
  const int ntl = t >> 6;
  const int l = t & 63;
  const int nt = ct * 4 + ntl;
  const int f = nt * 32 + kt;
  half8 o;
#pragma unroll
  for (int j = 0; j < 8; ++j)
    o[j] = (_Float16)tile[(l >> 4) * 8 + j][ntl * 16 + (l & 15)];
  *(half8*)(memTb + (size_t)(f * 64 + l) * 8) = o;
}

// c[m] = sum_e b[e] * mem[m][e]  (fp32). One wave per row.
__global__ __launch_bounds__(256) void bias_c(
    const float* __restrict__ b, const float* __restrict__ mem,
    float* __restrict__ c) {
  const int wave = threadIdx.x >> 6, lane = threadIdx.x & 63;
  const int row = blockIdx.x * 4 + wave;
  float s = 0.f;
#pragma unroll
  for (int j = 0; j < 16; ++j) {
    const int e = lane + 64 * j;
    s += b[e] * mem[row * 1024 + e];
  }
#pragma unroll
  for (int off = 32; off; off >>= 1) s += __shfl_xor(s, off);
  if (lane == 0) c[row] = s;
}

// ---------------------------------------------------------------------------
// Split-bf16 compensated GEMM for the small P = mem @ W product
// (128x128 tile, known-good structure). Epilogue writes C as bf16 hi/lo.
__global__ __launch_bounds__(256) void gemm_p(
    const __bf16* __restrict__ Agh, const __bf16* __restrict__ Agl,
    const __bf16* __restrict__ Bgh, const __bf16* __restrict__ Bgl,
    __bf16* __restrict__ Oh, __bf16* __restrict__ Ol) {
  __shared__ __attribute__((aligned(16))) __bf16 Ah[128 * 32];
  __shared__ __attribute__((aligned(16))) __bf16 Al[128 * 32];
  __shared__ __attribute__((aligned(16))) __bf16 Bh[128 * 32];
  __shared__ __attribute__((aligned(16))) __bf16 Bl[128 * 32];

  const int t = threadIdx.x;
  const int wave = t >> 6;
  const int lane = t & 63;
  const int wm = wave & 1, wn = wave >> 1;

  const int nwg = gridDim.x * gridDim.y;
  int flat = blockIdx.y * gridDim.x + blockIdx.x;
  if ((nwg & 7) == 0) {
    const int cpx = nwg >> 3;
    flat = (flat & 7) * cpx + (flat >> 3);
  }
  const int tileN = (flat % gridDim.x) * 128;
  const int tileM = (flat / gridDim.x) * 128;

  f32x4 acc[4][4] = {};

  const int rS = lane >> 2;
  const int cS = (lane & 3) * 8;

  for (int kt = 0; kt < KDIM / 32; ++kt) {
    const int k0 = kt * 32;
    __syncthreads();
#pragma unroll
    for (int i = 0; i < 2; ++i) {
      const int rb = i * 64 + wave * 16;
      const int grb = (tileN + rb + rS) * KDIM + k0 + cS;
      g2l16(Bgh + grb, &Bh[rb * 32]);
      g2l16(Bgl + grb, &Bl[rb * 32]);
      const int gra = (tileM + rb + rS) * KDIM + k0 + cS;
      g2l16(Agh + gra, &Ah[rb * 32]);
      g2l16(Agl + gra, &Al[rb * 32]);
    }
    __syncthreads();

    const int fr = lane & 15;
    const int fk = (lane >> 4) * 8;
    bf16x8 afh[4], afl[4], bfh[4], bfl[4];
#pragma unroll
    for (int mf = 0; mf < 4; ++mf) {
      const int r = wm * 64 + mf * 16 + fr;
      afh[mf] = *(const bf16x8*)(&Ah[r * 32 + fk]);
      afl[mf] = *(const bf16x8*)(&Al[r * 32 + fk]);
    }
#pragma unroll
    for (int nf = 0; nf < 4; ++nf) {
      const int r = wn * 64 + nf * 16 + fr;
      bfh[nf] = *(const bf16x8*)(&Bh[r * 32 + fk]);
      bfl[nf] = *(const bf16x8*)(&Bl[r * 32 + fk]);
    }
#pragma unroll
    for (int mf = 0; mf < 4; ++mf)
#pragma unroll
      for (int nf = 0; nf < 4; ++nf) {
        acc[mf][nf] = __builtin_amdgcn_mfma_f32_16x16x32_bf16(afh[mf], bfh[nf], acc[mf][nf], 0, 0, 0);
        acc[mf][nf] = __builtin_amdgcn_mfma_f32_16x16x32_bf16(afh[mf], bfl[nf], acc[mf][nf], 0, 0, 0);
        acc[mf][nf] = __builtin_amdgcn_mfma_f32_16x16x32_bf16(afl[mf], bfh[nf], acc[mf][nf], 0, 0, 0);
      }
  }

  const int er = (lane >> 4) * 4;
  const int ec = lane & 15;
#pragma unroll
  for (int nf = 0; nf < 4; ++nf) {
    const int col = tileN + wn * 64 + nf * 16 + ec;
#pragma unroll
    for (int mf = 0; mf < 4; ++mf) {
#pragma unroll
      for (int r = 0; r < 4; ++r) {
        const int row = tileM + wm * 64 + mf * 16 + er + r;
        const size_t idx = (size_t)row * KDIM + col;
        float v = acc[mf][nf][r];
        __bf16 h = (__bf16)v;
        Oh[idx] = h;
        Ol[idx] = (__bf16)(v - (float)h);
      }
    }
  }
}

// ---------------------------------------------------------------------------
// attn = x @ P^T + c : 256x256 tile, BK=32, 8 waves, 4 quadrant-phases/K-tile.
// EXACT round-6/8 version (best measured: 252 us, MfmaUtil 35, 0 bank conflicts).
__global__ __launch_bounds__(512, 2) void gemm_attn_8ph(
    const float* __restrict__ X,
    const __bf16* __restrict__ Pgh, const __bf16* __restrict__ Pgl,
    const float* __restrict__ bias,
    float* __restrict__ Of) {
  __shared__ __attribute__((aligned(16))) __bf16 AhL[2 * 8192];
  __shared__ __attribute__((aligned(16))) __bf16 AlL[2 * 8192];
  __shared__ __attribute__((aligned(16))) __bf16 BhL[2 * 8192];
  __shared__ __attribute__((aligned(16))) __bf16 BlL[2 * 8192];

  const int t = threadIdx.x;
  const int wave = t >> 6, lane = t & 63;
  const int wm = wave >> 2;        // 2 M-halves (128 rows each)
  const int wn = wave & 3;         // 4 N-quarters (64 cols each)

  // XCD-aware bijective remap; nwg = 4*128 = 512
  int flat = blockIdx.y * 4 + blockIdx.x;
  flat = (flat & 7) * 64 + (flat >> 3);
  const int tileN = (flat & 3) * 256;
  const int tileM = (flat >> 2) * 256;

  // ---- staging geometry
  int rowB_[2], gsB_[2], ldsB_[2];
#pragma unroll
  for (int i = 0; i < 2; ++i) {
    const int f16 = i * 512 + t;
    rowB_[i] = f16 >> 2;
    const int slot = f16 & 3;
    gsB_[i] = slot ^ ((rowB_[i] >> 1) & 3);       // pre-swizzled src col group
    ldsB_[i] = (i * 512 + wave * 64) * 8;         // wave-uniform elem base
  }
  int rowA_[4], colA_[4], physA_[4];
#pragma unroll
  for (int i = 0; i < 4; ++i) {
    const int f4 = i * 512 + t;
    rowA_[i] = f4 >> 3;
    const int col8 = f4 & 7;
    colA_[i] = col8 * 4;
    physA_[i] = rowA_[i] * 64 +
                ((((col8 >> 1) ^ ((rowA_[i] >> 1) & 3)) << 4)) + (col8 & 1) * 8;
  }

  const int fr = lane & 15;
  const int sc = lane >> 4;
  const int swF = (fr >> 1) & 3;
  const int fragoff = ((sc ^ swF) << 4);

  f32x4 acc[8][4] = {};
  f32x4 xr[4];

  auto xload = [&](int k0) {
#pragma unroll
    for (int i = 0; i < 4; ++i)
      xr[i] = *(const f32x4*)(X + (size_t)(tileM + rowA_[i]) * 1024 + k0 + colA_[i]);
  };
  auto stageB = [&](int buf, int k0) {
#pragma unroll
    for (int i = 0; i < 2; ++i) {
      const size_t g = (size_t)(tileN + rowB_[i]) * 1024 + k0 + gsB_[i] * 8;
      g2l16(Pgh + g, &BhL[buf * 8192 + ldsB_[i]]);
      g2l16(Pgl + g, &BlL[buf * 8192 + ldsB_[i]]);
    }
  };
  auto xwrite = [&](int buf) {
#pragma unroll
    for (int i = 0; i < 4; ++i) {
      bf16x4 h, l;
#pragma unroll
      for (int j = 0; j < 4; ++j) {
        const float vj = xr[i][j];
        __bf16 hh = (__bf16)vj;
        h[j] = hh;
        l[j] = (__bf16)(vj - (float)hh);
      }
      *(bf16x4*)((char*)AhL + buf * 16384 + physA_[i]) = h;
      *(bf16x4*)((char*)AlL + buf * 16384 + physA_[i]) = l;
    }
  };
  auto mm3 = [&](f32x4& a, const bf16x8& ah, const bf16x8& al,
                 const bf16x8& bh, const bf16x8& bl) {
    a = __builtin_amdgcn_mfma_f32_16x16x32_bf16(ah, bh, a, 0, 0, 0);
    a = __builtin_amdgcn_mfma_f32_16x16x32_bf16(ah, bl, a, 0, 0, 0);
    a = __builtin_amdgcn_mfma_f32_16x16x32_bf16(al, bh, a, 0, 0, 0);
  };

  // ---- prologue: stage K-tile 0 into buffer 0
  xload(0);
  stageB(0, 0);
  xwrite(0);   // compiler emits counted vmcnt for xr before the splits
  asm volatile("s_waitcnt vmcnt(0) lgkmcnt(0)" ::: "memory");
  __builtin_amdgcn_s_barrier();

  int cur = 0;
  for (int kt = 0; kt < 32; ++kt) {
    const int nxt = cur ^ 1;
    const int k1 = (kt + 1) * 32;
    bf16x8 ah[4], al[4], b0h[2], b0l[2], b1h[2], b1l[2];

    // ---- P0: read A m0-3 + B n0-1; issue next-tile x loads + B g2l16
#pragma unroll
    for (int mf = 0; mf < 4; ++mf) {
      const int row = wm * 128 + mf * 16 + fr;
      const int off = cur * 16384 + row * 64 + fragoff;
      ah[mf] = *(const bf16x8*)((const char*)AhL + off);
      al[mf] = *(const bf16x8*)((const char*)AlL + off);
    }
#pragma unroll
    for (int nf = 0; nf < 2; ++nf) {
      const int row = wn * 64 + nf * 16 + fr;
      const int off = cur * 16384 + row * 64 + fragoff;
      b0h[nf] = *(const bf16x8*)((const char*)BhL + off);
      b0l[nf] = *(const bf16x8*)((const char*)BlL + off);
    }
    if (kt < 31) { xload(k1); stageB(nxt, k1); }
    __builtin_amdgcn_s_barrier();
    __builtin_amdgcn_s_setprio(1);
#pragma unroll
    for (int mf = 0; mf < 4; ++mf)
#pragma unroll
      for (int nf = 0; nf < 2; ++nf)
        mm3(acc[mf][nf], ah[mf], al[mf], b0h[nf], b0l[nf]);
    __builtin_amdgcn_s_setprio(0);
    __builtin_amdgcn_s_barrier();

    // ---- P1: read B n2-3; MFMA m0-3 x n2-3
#pragma unroll
    for (int nf = 0; nf < 2; ++nf) {
      const int row = wn * 64 + (2 + nf) * 16 + fr;
      const int off = cur * 16384 + row * 64 + fragoff;
      b1h[nf] = *(const bf16x8*)((const char*)BhL + off);
      b1l[nf] = *(const bf16x8*)((const char*)BlL + off);
    }
    __builtin_amdgcn_s_barrier();
    __builtin_amdgcn_s_setprio(1);
#pragma unroll
    for (int mf = 0; mf < 4; ++mf)
#pragma unroll
      for (int nf = 0; nf < 2; ++nf)
        mm3(acc[mf][2 + nf], ah[mf], al[mf], b1h[nf], b1l[nf]);
    __builtin_amdgcn_s_setprio(0);
    __builtin_amdgcn_s_barrier();

    // ---- P2: read A m4-7; split+write next-tile A; MFMA m4-7 x n0-1
#pragma unroll
    for (int mf = 0; mf < 4; ++mf) {
      const int row = wm * 128 + (4 + mf) * 16 + fr;
      const int off = cur * 16384 + row * 64 + fragoff;
      ah[mf] = *(const bf16x8*)((const char*)AhL + off);
      al[mf] = *(const bf16x8*)((const char*)AlL + off);
    }
    if (kt < 31) xwrite(nxt);   // auto vmcnt(4): waits x loads, B stays in flight
    __builtin_amdgcn_s_barrier();
    __builtin_amdgcn_s_setprio(1);
#pragma unroll
    for (int mf = 0; mf < 4; ++mf)
#pragma unroll
      for (int nf = 0; nf < 2; ++nf)
        mm3(acc[4 + mf][nf], ah[mf], al[mf], b0h[nf], b0l[nf]);
    __builtin_amdgcn_s_setprio(0);
    __builtin_amdgcn_s_barrier();

    // ---- P3: MFMA m4-7 x n2-3; tile-end drain (ops are >=2 phases old)
    __builtin_amdgcn_s_setprio(1);
#pragma unroll
    for (int mf = 0; mf < 4; ++mf)
#pragma unroll
      for (int nf = 0; nf < 2; ++nf)
        mm3(acc[4 + mf][2 + nf], ah[mf], al[mf], b1h[nf], b1l[nf]);
    __builtin_amdgcn_s_setprio(0);
    asm volatile("s_waitcnt vmcnt(0) lgkmcnt(0)" ::: "memory");
    __builtin_amdgcn_s_barrier();
    cur = nxt;
  }

  // ---- epilogue: C/D layout col = lane&15, row = (lane>>4)*4 + reg; + bias
  const int er = (lane >> 4) * 4;
  const int ec = lane & 15;
#pragma unroll
  for (int nf = 0; nf < 4; ++nf) {
    const int col = tileN + wn * 64 + nf * 16 + ec;
    const float bv = bias[col];
#pragma unroll
    for (int mf = 0; mf < 8; ++mf) {
#pragma unroll
      for (int r = 0; r < 4; ++r) {
        const int row = tileM + wm * 128 + mf * 16 + er + r;
        Of[(size_t)row * 1024 + col] = acc[mf][nf][r] + bv;
      }
    }
  }
}

// ---------------------------------------------------------------------------
// Fused softmax + context GEMM, 64 rows/block, depth-3 B register pipeline.
// b-sets rotate b0/b1/b2; the set consumed at step kt was loaded at step kt-3
// -> ~2 full MFMA-steps (>=300 cyc) of L2-latency cover (depth-2 covered only
// ~1 step, the hypothesized per-step stall). Numerics identical to r8.
__global__ __launch_bounds__(512, 2) void fused_softmax_ctx64(
    const float* __restrict__ attn, const _Float16* __restrict__ memTb,
    float* __restrict__ out) {
  __shared__ __attribute__((aligned(16))) _Float16 P[64 * 1024];  // 128 KB

  const int t = threadIdx.x;
  const int wave = t >> 6, lane = t & 63;
  const int riw = lane >> 4;       // row within wave's 4-row group
  const int cg = lane & 15;        // col group (16 threads per row)
  const size_t grow0 = (size_t)blockIdx.x * 64;

  // B fragments for this wave: nt = wave*8 + nf; fragment (nf, kt) at
  // bb + (nf*32 + kt)*1024 bytes; lane's 16B slice at +lane*16.
  const char* bb = (const char*)memTb + (size_t)(wave * 256) * 1024 + lane * 16;

  // --- softmax: two passes of 32 rows (rows p*32 + wave*4 + riw)
#pragma unroll
  for (int p = 0; p < 2; ++p) {
    const int row = p * 32 + wave * 4 + riw;
    f32x4 v[16];
    {
      const f32x4* arow = (const f32x4*)(attn + (grow0 + row) * 1024);
#pragma unroll
      for (int j = 0; j < 16; ++j) v[j] = arow[cg + j * 16];
    }
    float m = -1e30f;
#pragma unroll
    for (int j = 0; j < 16; ++j)
      m = fmaxf(m, fmaxf(fmaxf(v[j].x, v[j].y), fmaxf(v[j].z, v[j].w)));
#pragma unroll
    for (int off = 1; off < 16; off <<= 1) m = fmaxf(m, __shfl_xor(m, off));

    float s = 0.f;
#pragma unroll
    for (int j = 0; j < 16; ++j) {
      v[j].x = expf(v[j].x - m);
      v[j].y = expf(v[j].y - m);
      v[j].z = expf(v[j].z - m);
      v[j].w = expf(v[j].w - m);
      s += (v[j].x + v[j].y) + (v[j].z + v[j].w);
    }
#pragma unroll
    for (int off = 1; off < 16; off <<= 1) s += __shfl_xor(s, off);
    const float inv = 1.0f / s;

    const int swz = (row & 7) << 4;
    char* rbase = (char*)P + row * 2048;
#pragma unroll
    for (int j = 0; j < 16; ++j) {
      half4v o;
      o[0] = (_Float16)(v[j].x * inv);
      o[1] = (_Float16)(v[j].y * inv);
      o[2] = (_Float16)(v[j].z * inv);
      o[3] = (_Float16)(v[j].w * inv);
      const int byteoff = (cg * 8 + j * 128) ^ swz;   // 8B-aligned, bijective
      *(half4v*)(rbase + byteoff) = o;
    }
  }

  // prefetch B-frags for kt=0,1,2 (stay in flight across the barrier)
  half8 b0[8], b1[8], b2[8];
#pragma unroll
  for (int nf = 0; nf < 8; ++nf)
    b0[nf] = *(const half8*)(bb + nf * 32768);
#pragma unroll
  for (int nf = 0; nf < 8; ++nf)
    b1[nf] = *(const half8*)(bb + nf * 32768 + 1024);
#pragma unroll
  for (int nf = 0; nf < 8; ++nf)
    b2[nf] = *(const half8*)(bb + nf * 32768 + 2048);

  __syncthreads();

  // --- context GEMM: out[64 rows][wave's 128 cols] = P @ mem
  const int fr = lane & 15;
  const int fko = (lane >> 4) * 8;   // k element offset within 32
  f32x4 acc[4][8] = {};

  auto step = [&](half8 (&bc)[8], int kt) {
    half8 a[4];
#pragma unroll
    for (int mf = 0; mf < 4; ++mf) {
      const int ar = mf * 16 + fr;
      const int kbyte = ((kt * 32 + fko) * 2) ^ ((ar & 7) << 4);
      a[mf] = *(const half8*)((const char*)P + ar * 2048 + kbyte);
    }
#pragma unroll
    for (int mf = 0; mf < 4; ++mf)
#pragma unroll
      for (int nf = 0; nf < 8; ++nf)
        acc[mf][nf] = __builtin_amdgcn_mfma_f32_16x16x32_f16(a[mf], bc[nf], acc[mf][nf], 0, 0, 0);
    if (kt + 3 < 32) {
#pragma unroll
      for (int nf = 0; nf < 8; ++nf)
        bc[nf] = *(const half8*)(bb + nf * 32768 + (kt + 3) * 1024);
    }
  };

  for (int kt = 0; kt < 30; kt += 3) {
    step(b0, kt);
    step(b1, kt + 1);
    step(b2, kt + 2);
  }
  step(b0, 30);
  step(b1, 31);

  // --- epilogue. C/D layout: col = lane&15, row = (lane>>4)*4 + reg
  const int colbase = wave * 128;
  const int er = (lane >> 4) * 4;
  const int ec = lane & 15;
#pragma unroll
  for (int mf = 0; mf < 4; ++mf)
#pragma unroll
    for (int nf = 0; nf < 8; ++nf) {
      const int col = colbase + nf * 16 + ec;
#pragma unroll
      for (int r = 0; r < 4; ++r)
        out[(grow0 + mf * 16 + er + r) * 1024 + col] = acc[mf][nf][r];
    }
}

// ---------------------------------------------------------------------------
extern "C" void kernel_launch(void* const* d_in, const int* in_sizes, int n_in,
                              void* d_out, int out_size, void* d_ws, size_t ws_size,
                              hipStream_t stream) {
  const float* x   = (const float*)d_in[0];   // [32768][1024]
  const float* W   = (const float*)d_in[1];   // [1024][1024]  (out=e, in=d)
  const float* b   = (const float*)d_in[2];   // [1024]
  const float* mem = (const float*)d_in[3];   // [1024][1024]  (m, e)
  float* out = (float*)d_out;

  char* ws = (char*)d_ws;
  const size_t MB = 1024 * 1024;
  float*    attn  = (float*)(ws);              // 128 MB
  __bf16*   Mh    = (__bf16*)(ws + 192 * MB);  // 2 MB
  __bf16*   Ml    = (__bf16*)(ws + 194 * MB);  // 2 MB
  __bf16*   Wth   = (__bf16*)(ws + 196 * MB);  // 2 MB
  __bf16*   Wtl   = (__bf16*)(ws + 198 * MB);  // 2 MB
  __bf16*   Ph    = (__bf16*)(ws + 200 * MB);  // 2 MB
  __bf16*   Pl    = (__bf16*)(ws + 202 * MB);  // 2 MB
  _Float16* memTb = (_Float16*)(ws + 204 * MB);// 2 MB
  float*    cvec  = (float*)(ws + 206 * MB);   // 4 KB

  // preps (all tiny)
  split_mem<<<4096, 256, 0, stream>>>(mem, Mh, Ml);
  transpose_split_W<<<dim3(32, 32), dim3(32, 8), 0, stream>>>(W, Wth, Wtl);
  build_memTb<<<512, 256, 0, stream>>>(mem, memTb);
  bias_c<<<256, 256, 0, stream>>>(b, mem, cvec);

  // P = mem @ W  (split-bf16, out split bf16)
  gemm_p<<<dim3(8, 8), 256, 0, stream>>>(Mh, Ml, Wth, Wtl, Ph, Pl);

  // attn = x @ P^T + c  (r6 256x256 4-phase, 252 us known-good)
  gemm_attn_8ph<<<dim3(4, 128), 512, 0, stream>>>(x, Ph, Pl, cvec, attn);

  // fused softmax + context = probs @ mem  (64 rows/block, depth-3 B pipeline)
  fused_softmax_ctx64<<<512, 512, 0, stream>>>(attn, memTb, out);
}